// Round 1
// baseline (32.512 us; speedup 1.0000x reference)
//
#include <hip/hip_runtime.h>

// HeuristicBimodalCSRPool: per CSR segment, argmax (first index on ties) of
// x_proj[:, 0], gather that x_mod row, plus a "seen" flag.
// One 64-lane wave per group; 4 groups per 256-thread block.

__global__ void __launch_bounds__(256)
csr_pool_kernel(const float* __restrict__ x_mod,
                const float* __restrict__ x_proj,
                const int* __restrict__ csr_idx,
                float* __restrict__ out_pool,
                float* __restrict__ out_seen,
                int n_groups, int n_elem) {
    const int lane = threadIdx.x & 63;
    const int wave = threadIdx.x >> 6;
    const int g = blockIdx.x * 4 + wave;
    if (g >= n_groups) return;

    const int start = csr_idx[g];
    const int end   = csr_idx[g + 1];

    // Per-lane scan: keep max value, first index achieving it.
    float best = -__builtin_inff();
    int   bidx = n_elem;  // sentinel (also matches reference's "cand" fill)
    for (int e = start + lane; e < end; e += 64) {
        float v = x_proj[(size_t)e * 8];   // FEAT = 0, N_PROJ = 8
        if (v > best) { best = v; bidx = e; }   // indices ascend per-lane, so strict '>' keeps first max
    }

    // Wave butterfly reduce: (max value, min index on equal value).
    #pragma unroll
    for (int off = 32; off >= 1; off >>= 1) {
        float ov = __shfl_xor(best, off);
        int   oi = __shfl_xor(bidx, off);
        if (ov > best || (ov == best && oi < bidx)) { best = ov; bidx = oi; }
    }

    const bool seen = end > start;
    if (lane == 0) out_seen[g] = seen ? 1.0f : 0.0f;

    // Gather the winning row (64 floats, one per lane — coalesced 256 B).
    const int row = seen ? bidx : 0;
    float v = seen ? x_mod[(size_t)row * 64 + lane] : 0.0f;
    out_pool[(size_t)g * 64 + lane] = v;
}

extern "C" void kernel_launch(void* const* d_in, const int* in_sizes, int n_in,
                              void* d_out, int out_size, void* d_ws, size_t ws_size,
                              hipStream_t stream) {
    // setup_inputs order: x_main (unused), x_mod, x_proj, csr_idx
    const float* x_mod  = (const float*)d_in[1];
    const float* x_proj = (const float*)d_in[2];
    const int*   csr    = (const int*)d_in[3];

    const int n_groups = in_sizes[3] - 1;     // csr_idx has n_groups+1 entries
    const int n_elem   = in_sizes[1] / 64;    // x_mod is (E, 64)

    float* out_pool = (float*)d_out;
    float* out_seen = out_pool + (size_t)n_groups * 64;

    const int groups_per_block = 4;           // 4 waves of 64
    dim3 block(256);
    dim3 grid((n_groups + groups_per_block - 1) / groups_per_block);
    csr_pool_kernel<<<grid, block, 0, stream>>>(x_mod, x_proj, csr, out_pool,
                                                out_seen, n_groups, n_elem);
}

// Round 2
// 20.343 us; speedup vs baseline: 1.5981x; 1.5981x over previous
//
#include <hip/hip_runtime.h>

// HeuristicBimodalCSRPool: per CSR segment, argmax (first index on ties) of
// x_proj[:, 0], gather that x_mod row (64 f32), plus a "seen" flag.
// 16 lanes per group -> 4 groups per wave, 16 groups per 256-thread block.
// Row gather/write is one float4 per lane (fully coalesced 256 B).

__global__ void __launch_bounds__(256)
csr_pool_kernel(const float* __restrict__ x_mod,
                const float* __restrict__ x_proj,
                const int* __restrict__ csr_idx,
                float* __restrict__ out_pool,
                float* __restrict__ out_seen,
                int n_groups, int n_elem) {
    const int lane16 = threadIdx.x & 15;
    const int g = blockIdx.x * 16 + (threadIdx.x >> 4);
    if (g >= n_groups) return;

    const int start = csr_idx[g];
    const int end   = csr_idx[g + 1];

    // Per-lane scan: keep max value, first index achieving it.
    float best = -__builtin_inff();
    int   bidx = n_elem;  // sentinel
    for (int e = start + lane16; e < end; e += 16) {
        float v = x_proj[(size_t)e * 8];      // FEAT = 0, N_PROJ = 8
        if (v > best) { best = v; bidx = e; } // per-lane indices ascend -> strict '>' keeps first
    }

    // Subgroup (16-lane) butterfly reduce: max value, min index on ties.
    // xor offsets < 16 keep lanes within their 16-lane subgroup.
    #pragma unroll
    for (int off = 8; off >= 1; off >>= 1) {
        float ov = __shfl_xor(best, off);
        int   oi = __shfl_xor(bidx, off);
        if (ov > best || (ov == best && oi < bidx)) { best = ov; bidx = oi; }
    }

    const bool seen = end > start;
    if (lane16 == 0) out_seen[g] = seen ? 1.0f : 0.0f;

    // Gather winning row: 16 lanes x float4 = 256 B coalesced.
    const int row = seen ? bidx : 0;
    const float4* src = (const float4*)(x_mod) + (size_t)row * 16 + lane16;
    float4 v;
    if (seen) {
        v = *src;
    } else {
        v = make_float4(0.f, 0.f, 0.f, 0.f);
    }
    ((float4*)out_pool)[(size_t)g * 16 + lane16] = v;
}

extern "C" void kernel_launch(void* const* d_in, const int* in_sizes, int n_in,
                              void* d_out, int out_size, void* d_ws, size_t ws_size,
                              hipStream_t stream) {
    // setup_inputs order: x_main (unused), x_mod, x_proj, csr_idx
    const float* x_mod  = (const float*)d_in[1];
    const float* x_proj = (const float*)d_in[2];
    const int*   csr    = (const int*)d_in[3];

    const int n_groups = in_sizes[3] - 1;     // csr_idx has n_groups+1 entries
    const int n_elem   = in_sizes[1] / 64;    // x_mod is (E, 64)

    float* out_pool = (float*)d_out;
    float* out_seen = out_pool + (size_t)n_groups * 64;

    const int groups_per_block = 16;          // 16 lanes per group
    dim3 block(256);
    dim3 grid((n_groups + groups_per_block - 1) / groups_per_block);
    csr_pool_kernel<<<grid, block, 0, stream>>>(x_mod, x_proj, csr, out_pool,
                                                out_seen, n_groups, n_elem);
}